// Round 5
// baseline (136.729 us; speedup 1.0000x reference)
//
#include <hip/hip_runtime.h>
#include <math.h>

#define TPB 128   // 2 waves: deeper per-thread loops on avg-2048 segments, more blocks/CU

__global__ __launch_bounds__(TPB) void jls_kernel(
    const float* __restrict__ x,
    const int* __restrict__ prefix,
    float* __restrict__ out)
{
    const int seg   = blockIdx.x;
    const int start = (seg == 0) ? 0 : prefix[seg - 1];
    const int end   = prefix[seg];
    if (end <= start) return;           // empty segment (uniform across block)

    const int tid = threadIdx.x;

    // alignment split: [start,a0) scalar head, [a0,a1) float4 body, [a1,end) scalar tail
    int a0 = (start + 3) & ~3;  if (a0 > end) a0 = end;
    int a1 = end & ~3;          if (a1 < a0) a1 = a0;
    const float4* __restrict__ x4 = (const float4*)x;
    const int v0 = a0 >> 2, v1 = a1 >> 2;

    __shared__ float sbuf[2];   // 2 waves per block

    // ---------------- pass 1: segment max ----------------
    float m = -INFINITY;
    for (int i = start + tid; i < a0; i += TPB) m = fmaxf(m, x[i]);
    for (int i = v0 + tid; i < v1; i += TPB) {
        float4 v = x4[i];
        m = fmaxf(m, fmaxf(fmaxf(v.x, v.y), fmaxf(v.z, v.w)));
    }
    for (int i = a1 + tid; i < end; i += TPB) m = fmaxf(m, x[i]);

    #pragma unroll
    for (int off = 32; off > 0; off >>= 1)
        m = fmaxf(m, __shfl_xor(m, off, 64));
    if ((tid & 63) == 0) sbuf[tid >> 6] = m;
    __syncthreads();
    m = fmaxf(sbuf[0], sbuf[1]);
    __syncthreads();    // protect sbuf for reuse below

    // ---------------- pass 2: sum of exp(x - m) ----------------
    float l = 0.0f;
    for (int i = start + tid; i < a0; i += TPB) l += __expf(x[i] - m);
    for (int i = v0 + tid; i < v1; i += TPB) {
        float4 v = x4[i];
        l += __expf(v.x - m) + __expf(v.y - m) + __expf(v.z - m) + __expf(v.w - m);
    }
    for (int i = a1 + tid; i < end; i += TPB) l += __expf(x[i] - m);

    #pragma unroll
    for (int off = 32; off > 0; off >>= 1)
        l += __shfl_xor(l, off, 64);
    if ((tid & 63) == 0) sbuf[tid >> 6] = l;
    __syncthreads();
    l = sbuf[0] + sbuf[1];

    const float c = m + __logf(l);

    // ---------------- pass 3: write out = x - c ----------------
    float4* __restrict__ o4 = (float4*)out;
    for (int i = start + tid; i < a0; i += TPB) out[i] = x[i] - c;
    for (int i = v0 + tid; i < v1; i += TPB) {
        float4 v = x4[i];
        float4 r;
        r.x = v.x - c; r.y = v.y - c; r.z = v.z - c; r.w = v.w - c;
        o4[i] = r;
    }
    for (int i = a1 + tid; i < end; i += TPB) out[i] = x[i] - c;
}

extern "C" void kernel_launch(void* const* d_in, const int* in_sizes, int n_in,
                              void* d_out, int out_size, void* d_ws, size_t ws_size,
                              hipStream_t stream) {
    const float* logits = (const float*)d_in[0];
    const int*   prefix = (const int*)d_in[1];
    float*       out    = (float*)d_out;
    const int num_segs  = in_sizes[1];

    jls_kernel<<<num_segs, TPB, 0, stream>>>(logits, prefix, out);
}

// Round 6
// 119.971 us; speedup vs baseline: 1.1397x; 1.1397x over previous
//
#include <hip/hip_runtime.h>
#include <math.h>

#define TPB 256   // 256 proven better than 128: concurrent-segment working set stays within L2

__device__ __forceinline__ float max4(float4 v) {
    return fmaxf(fmaxf(v.x, v.y), fmaxf(v.z, v.w));
}

// combine two online-softmax states (m,l) <- (m,l) ⊕ (mo,lo); l==0 guard avoids exp(-inf+inf)=NaN
__device__ __forceinline__ void combine(float& m, float& l, float mo, float lo) {
    float mn = fmaxf(m, mo);
    float a = (l  > 0.0f) ? l  * __expf(m  - mn) : 0.0f;
    float b = (lo > 0.0f) ? lo * __expf(mo - mn) : 0.0f;
    m = mn;
    l = a + b;
}

__global__ __launch_bounds__(TPB) void jls_kernel(
    const float* __restrict__ x,
    const int* __restrict__ prefix,
    float* __restrict__ out)
{
    const int seg   = blockIdx.x;
    const int start = (seg == 0) ? 0 : prefix[seg - 1];
    const int end   = prefix[seg];
    if (end <= start) return;           // empty segment (uniform across block)

    const int tid = threadIdx.x;

    // alignment split: [start,a0) scalar head, [a0,a1) float4 body, [a1,end) scalar tail
    int a0 = (start + 3) & ~3;  if (a0 > end) a0 = end;
    int a1 = end & ~3;          if (a1 < a0) a1 = a0;
    const float4* __restrict__ x4 = (const float4*)x;
    const int v0 = a0 >> 2, v1 = a1 >> 2;

    // ---------------- pass 1: fused online max+sumexp (single global read) ----
    float m0 = -INFINITY, l0 = 0.0f;
    float m1 = -INFINITY, l1 = 0.0f;
    int i = v0 + tid;
    for (; i + TPB < v1; i += 2 * TPB) {
        float4 a = x4[i];
        float4 b = x4[i + TPB];
        float am = max4(a), bm = max4(b);
        if (am > m0) { l0 *= __expf(m0 - am); m0 = am; }
        l0 += __expf(a.x - m0) + __expf(a.y - m0) + __expf(a.z - m0) + __expf(a.w - m0);
        if (bm > m1) { l1 *= __expf(m1 - bm); m1 = bm; }
        l1 += __expf(b.x - m1) + __expf(b.y - m1) + __expf(b.z - m1) + __expf(b.w - m1);
    }
    if (i < v1) {
        float4 a = x4[i];
        float am = max4(a);
        if (am > m0) { l0 *= __expf(m0 - am); m0 = am; }
        l0 += __expf(a.x - m0) + __expf(a.y - m0) + __expf(a.z - m0) + __expf(a.w - m0);
    }
    for (int j = start + tid; j < a0; j += TPB) {
        float v = x[j];
        if (v > m0) { l0 *= __expf(m0 - v); m0 = v; }
        l0 += __expf(v - m0);
    }
    for (int j = a1 + tid; j < end; j += TPB) {
        float v = x[j];
        if (v > m1) { l1 *= __expf(m1 - v); m1 = v; }
        l1 += __expf(v - m1);
    }
    combine(m0, l0, m1, l1);

    // joint (m,l) reduction: 6 shfl rounds + one LDS round (single barrier)
    #pragma unroll
    for (int off = 32; off > 0; off >>= 1) {
        float mo = __shfl_xor(m0, off, 64);
        float lo = __shfl_xor(l0, off, 64);
        combine(m0, l0, mo, lo);
    }
    __shared__ float sm[4], sl[4];
    if ((tid & 63) == 0) { sm[tid >> 6] = m0; sl[tid >> 6] = l0; }
    __syncthreads();
    float M = sm[0], L = sl[0];
    combine(M, L, sm[1], sl[1]);
    combine(M, L, sm[2], sl[2]);
    combine(M, L, sm[3], sl[3]);

    const float c = M + __logf(L);

    // ---------------- pass 2: write out = x - c (L2-warm re-read, 2-deep) ------
    float4* __restrict__ o4 = (float4*)out;
    i = v0 + tid;
    for (; i + TPB < v1; i += 2 * TPB) {
        float4 a = x4[i];
        float4 b = x4[i + TPB];
        float4 ra, rb;
        ra.x = a.x - c; ra.y = a.y - c; ra.z = a.z - c; ra.w = a.w - c;
        rb.x = b.x - c; rb.y = b.y - c; rb.z = b.z - c; rb.w = b.w - c;
        o4[i] = ra;
        o4[i + TPB] = rb;
    }
    if (i < v1) {
        float4 a = x4[i];
        float4 ra;
        ra.x = a.x - c; ra.y = a.y - c; ra.z = a.z - c; ra.w = a.w - c;
        o4[i] = ra;
    }
    for (int j = start + tid; j < a0; j += TPB) out[j] = x[j] - c;
    for (int j = a1 + tid;   j < end; j += TPB) out[j] = x[j] - c;
}

extern "C" void kernel_launch(void* const* d_in, const int* in_sizes, int n_in,
                              void* d_out, int out_size, void* d_ws, size_t ws_size,
                              hipStream_t stream) {
    const float* logits = (const float*)d_in[0];
    const int*   prefix = (const int*)d_in[1];
    float*       out    = (float*)d_out;
    const int num_segs  = in_sizes[1];

    jls_kernel<<<num_segs, TPB, 0, stream>>>(logits, prefix, out);
}

// Round 7
// 116.906 us; speedup vs baseline: 1.1696x; 1.0262x over previous
//
#include <hip/hip_runtime.h>
#include <math.h>

#define TPB 256   // 256 proven better than 128: concurrent-segment working set stays within L2

__device__ __forceinline__ float max4(float4 v) {
    return fmaxf(fmaxf(v.x, v.y), fmaxf(v.z, v.w));
}

// combine two online-softmax states (m,l) <- (m,l) ⊕ (mo,lo); l==0 guard avoids exp(-inf+inf)=NaN
__device__ __forceinline__ void combine(float& m, float& l, float mo, float lo) {
    float mn = fmaxf(m, mo);
    float a = (l  > 0.0f) ? l  * __expf(m  - mn) : 0.0f;
    float b = (lo > 0.0f) ? lo * __expf(mo - mn) : 0.0f;
    m = mn;
    l = a + b;
}

__device__ __forceinline__ void acc4(float4 a, float& m, float& l) {
    float am = max4(a);
    if (am > m) { l *= __expf(m - am); m = am; }
    l += __expf(a.x - m) + __expf(a.y - m) + __expf(a.z - m) + __expf(a.w - m);
}

__global__ __launch_bounds__(TPB) void jls_kernel(
    const float* __restrict__ x,
    const int* __restrict__ prefix,
    float* __restrict__ out)
{
    const int seg   = blockIdx.x;
    const int start = (seg == 0) ? 0 : prefix[seg - 1];
    const int end   = prefix[seg];
    if (end <= start) return;           // empty segment (uniform across block)

    const int tid = threadIdx.x;

    // alignment split: [start,a0) scalar head, [a0,a1) float4 body, [a1,end) scalar tail
    int a0 = (start + 3) & ~3;  if (a0 > end) a0 = end;
    int a1 = end & ~3;          if (a1 < a0) a1 = a0;
    const float4* __restrict__ x4 = (const float4*)x;
    const int v0 = a0 >> 2, v1 = a1 >> 2;

    const int i0 = v0 + tid;
    const bool h0 = (i0            < v1);
    const bool h1 = (i0 +     TPB  < v1);
    const bool h2 = (i0 + 2 * TPB  < v1);
    const bool h3 = (i0 + 3 * TPB  < v1);

    // ---------------- pass 1: fused online max+sumexp, register-cached head ----
    // First 4 float4-iterations held in registers (segments <= 4096 elts fully cached).
    float4 r0, r1, r2, r3;
    float m0 = -INFINITY, l0 = 0.0f;
    float m1 = -INFINITY, l1 = 0.0f;
    if (h0) r0 = x4[i0];
    if (h1) r1 = x4[i0 + TPB];
    if (h2) r2 = x4[i0 + 2 * TPB];
    if (h3) r3 = x4[i0 + 3 * TPB];
    if (h0) acc4(r0, m0, l0);
    if (h1) acc4(r1, m1, l1);
    if (h2) acc4(r2, m0, l0);
    if (h3) acc4(r3, m1, l1);

    int i = i0 + 4 * TPB;
    for (; i + TPB < v1; i += 2 * TPB) {
        float4 a = x4[i];
        float4 b = x4[i + TPB];
        acc4(a, m0, l0);
        acc4(b, m1, l1);
    }
    if (i < v1) acc4(x4[i], m0, l0);

    for (int j = start + tid; j < a0; j += TPB) {
        float v = x[j];
        if (v > m0) { l0 *= __expf(m0 - v); m0 = v; }
        l0 += __expf(v - m0);
    }
    for (int j = a1 + tid; j < end; j += TPB) {
        float v = x[j];
        if (v > m1) { l1 *= __expf(m1 - v); m1 = v; }
        l1 += __expf(v - m1);
    }
    combine(m0, l0, m1, l1);

    // joint (m,l) reduction: 6 shfl rounds + one LDS round (single barrier)
    #pragma unroll
    for (int off = 32; off > 0; off >>= 1) {
        float mo = __shfl_xor(m0, off, 64);
        float lo = __shfl_xor(l0, off, 64);
        combine(m0, l0, mo, lo);
    }
    __shared__ float sm[4], sl[4];
    if ((tid & 63) == 0) { sm[tid >> 6] = m0; sl[tid >> 6] = l0; }
    __syncthreads();
    float M = sm[0], L = sl[0];
    combine(M, L, sm[1], sl[1]);
    combine(M, L, sm[2], sl[2]);
    combine(M, L, sm[3], sl[3]);

    const float c = M + __logf(L);

    // ---------------- pass 2: write out = x - c ---------------------------------
    // Cached head straight from registers (no re-read); remainder L2-warm re-read.
    float4* __restrict__ o4 = (float4*)out;
    if (h0) { float4 r; r.x = r0.x - c; r.y = r0.y - c; r.z = r0.z - c; r.w = r0.w - c; o4[i0]           = r; }
    if (h1) { float4 r; r.x = r1.x - c; r.y = r1.y - c; r.z = r1.z - c; r.w = r1.w - c; o4[i0 + TPB]     = r; }
    if (h2) { float4 r; r.x = r2.x - c; r.y = r2.y - c; r.z = r2.z - c; r.w = r2.w - c; o4[i0 + 2 * TPB] = r; }
    if (h3) { float4 r; r.x = r3.x - c; r.y = r3.y - c; r.z = r3.z - c; r.w = r3.w - c; o4[i0 + 3 * TPB] = r; }

    i = i0 + 4 * TPB;
    for (; i + TPB < v1; i += 2 * TPB) {
        float4 a = x4[i];
        float4 b = x4[i + TPB];
        float4 ra, rb;
        ra.x = a.x - c; ra.y = a.y - c; ra.z = a.z - c; ra.w = a.w - c;
        rb.x = b.x - c; rb.y = b.y - c; rb.z = b.z - c; rb.w = b.w - c;
        o4[i] = ra;
        o4[i + TPB] = rb;
    }
    if (i < v1) {
        float4 a = x4[i];
        float4 ra;
        ra.x = a.x - c; ra.y = a.y - c; ra.z = a.z - c; ra.w = a.w - c;
        o4[i] = ra;
    }
    for (int j = start + tid; j < a0; j += TPB) out[j] = x[j] - c;
    for (int j = a1 + tid;   j < end; j += TPB) out[j] = x[j] - c;
}

extern "C" void kernel_launch(void* const* d_in, const int* in_sizes, int n_in,
                              void* d_out, int out_size, void* d_ws, size_t ws_size,
                              hipStream_t stream) {
    const float* logits = (const float*)d_in[0];
    const int*   prefix = (const int*)d_in[1];
    float*       out    = (float*)d_out;
    const int num_segs  = in_sizes[1];

    jls_kernel<<<num_segs, TPB, 0, stream>>>(logits, prefix, out);
}

// Round 9
// 114.800 us; speedup vs baseline: 1.1910x; 1.0183x over previous
//
#include <hip/hip_runtime.h>
#include <math.h>

#define TPB 256   // 256 proven better than 128 (R5: more concurrent segments thrashed L2)
#define NC  8     // cached float4 iters/thread: segments <= 8192 elts fully register-resident (~91% of mass)

// native clang vector for nontemporal builtin (HIP float4 is a class — rejected)
typedef float vfloat4 __attribute__((ext_vector_type(4)));

__device__ __forceinline__ float max4(float4 v) {
    return fmaxf(fmaxf(v.x, v.y), fmaxf(v.z, v.w));
}

__device__ __forceinline__ void nt_store4(float4 r, float4* p) {
    vfloat4 v = {r.x, r.y, r.z, r.w};
    __builtin_nontemporal_store(v, (vfloat4*)p);
}

// combine two online-softmax states (m,l) <- (m,l) ⊕ (mo,lo); l==0 guard avoids exp(-inf+inf)=NaN
__device__ __forceinline__ void combine(float& m, float& l, float mo, float lo) {
    float mn = fmaxf(m, mo);
    float a = (l  > 0.0f) ? l  * __expf(m  - mn) : 0.0f;
    float b = (lo > 0.0f) ? lo * __expf(mo - mn) : 0.0f;
    m = mn;
    l = a + b;
}

__device__ __forceinline__ void acc4(float4 a, float& m, float& l) {
    float am = max4(a);
    if (am > m) { l *= __expf(m - am); m = am; }
    l += __expf(a.x - m) + __expf(a.y - m) + __expf(a.z - m) + __expf(a.w - m);
}

__global__ __launch_bounds__(TPB) void jls_kernel(
    const float* __restrict__ x,
    const int* __restrict__ prefix,
    float* __restrict__ out)
{
    const int seg   = blockIdx.x;
    const int start = (seg == 0) ? 0 : prefix[seg - 1];
    const int end   = prefix[seg];
    if (end <= start) return;           // empty segment (uniform across block)

    const int tid = threadIdx.x;

    // alignment split: [start,a0) scalar head, [a0,a1) float4 body, [a1,end) scalar tail
    int a0 = (start + 3) & ~3;  if (a0 > end) a0 = end;
    int a1 = end & ~3;          if (a1 < a0) a1 = a0;
    const float4* __restrict__ x4 = (const float4*)x;
    const int v0 = a0 >> 2, v1 = a1 >> 2;

    const int i0 = v0 + tid;

    // ---------------- pass 1: fused online max+sumexp, register-cached head ----
    float4 rc[NC];
    bool   hv[NC];
    #pragma unroll
    for (int k = 0; k < NC; ++k) {
        hv[k] = (i0 + k * TPB) < v1;
        if (hv[k]) rc[k] = x4[i0 + k * TPB];
    }

    float m0 = -INFINITY, l0 = 0.0f;
    float m1 = -INFINITY, l1 = 0.0f;
    #pragma unroll
    for (int k = 0; k < NC; ++k) {
        if (hv[k]) {
            if (k & 1) acc4(rc[k], m1, l1);
            else       acc4(rc[k], m0, l0);
        }
    }

    int i = i0 + NC * TPB;
    for (; i + TPB < v1; i += 2 * TPB) {
        float4 a = x4[i];
        float4 b = x4[i + TPB];
        acc4(a, m0, l0);
        acc4(b, m1, l1);
    }
    if (i < v1) acc4(x4[i], m0, l0);

    for (int j = start + tid; j < a0; j += TPB) {
        float v = x[j];
        if (v > m0) { l0 *= __expf(m0 - v); m0 = v; }
        l0 += __expf(v - m0);
    }
    for (int j = a1 + tid; j < end; j += TPB) {
        float v = x[j];
        if (v > m1) { l1 *= __expf(m1 - v); m1 = v; }
        l1 += __expf(v - m1);
    }
    combine(m0, l0, m1, l1);

    // joint (m,l) reduction: 6 shfl rounds + one LDS round (single barrier)
    #pragma unroll
    for (int off = 32; off > 0; off >>= 1) {
        float mo = __shfl_xor(m0, off, 64);
        float lo = __shfl_xor(l0, off, 64);
        combine(m0, l0, mo, lo);
    }
    __shared__ float sm[4], sl[4];
    if ((tid & 63) == 0) { sm[tid >> 6] = m0; sl[tid >> 6] = l0; }
    __syncthreads();
    float M = sm[0], L = sl[0];
    combine(M, L, sm[1], sl[1]);
    combine(M, L, sm[2], sl[2]);
    combine(M, L, sm[3], sl[3]);

    const float c = M + __logf(L);

    // ---------------- pass 2: write out = x - c ---------------------------------
    // Cached head straight from registers; ALL stores non-temporal (output is never
    // re-read — keep L2 reserved for x re-reads of >8192-elt segments).
    float4* __restrict__ o4 = (float4*)out;
    #pragma unroll
    for (int k = 0; k < NC; ++k) {
        if (hv[k]) {
            float4 r;
            r.x = rc[k].x - c; r.y = rc[k].y - c; r.z = rc[k].z - c; r.w = rc[k].w - c;
            nt_store4(r, &o4[i0 + k * TPB]);
        }
    }

    i = i0 + NC * TPB;
    for (; i + TPB < v1; i += 2 * TPB) {
        float4 a = x4[i];
        float4 b = x4[i + TPB];
        float4 ra, rb;
        ra.x = a.x - c; ra.y = a.y - c; ra.z = a.z - c; ra.w = a.w - c;
        rb.x = b.x - c; rb.y = b.y - c; rb.z = b.z - c; rb.w = b.w - c;
        nt_store4(ra, &o4[i]);
        nt_store4(rb, &o4[i + TPB]);
    }
    if (i < v1) {
        float4 a = x4[i];
        float4 ra;
        ra.x = a.x - c; ra.y = a.y - c; ra.z = a.z - c; ra.w = a.w - c;
        nt_store4(ra, &o4[i]);
    }
    for (int j = start + tid; j < a0; j += TPB) __builtin_nontemporal_store(x[j] - c, &out[j]);
    for (int j = a1 + tid;   j < end; j += TPB) __builtin_nontemporal_store(x[j] - c, &out[j]);
}

extern "C" void kernel_launch(void* const* d_in, const int* in_sizes, int n_in,
                              void* d_out, int out_size, void* d_ws, size_t ws_size,
                              hipStream_t stream) {
    const float* logits = (const float*)d_in[0];
    const int*   prefix = (const int*)d_in[1];
    float*       out    = (float*)d_out;
    const int num_segs  = in_sizes[1];

    jls_kernel<<<num_segs, TPB, 0, stream>>>(logits, prefix, out);
}